// Round 2
// baseline (62.656 us; speedup 1.0000x reference)
//
#include <hip/hip_runtime.h>
#include <math.h>

#define BB 32
#define TT 50
#define HH 52
#define WW 52
#define NB 3
#define NC 80
#define CE 85            // 5 + NC
#define SP (HH*WW)       // 2704
#define NCELL (BB*NB*SP) // 259584
#define EPSF 1e-7f

#define NTHR_LOSS 256
#define CELLS_PER_THR 4
#define NBLK_LOSS ((NCELL / CELLS_PER_THR + NTHR_LOSS - 1) / NTHR_LOSS)  // 254

__device__ __forceinline__ float sigmoid_clamped(float z) {
    float p = 1.0f / (1.0f + expf(-z));
    return fminf(fmaxf(p, EPSF), 1.0f - EPSF);
}

__device__ __forceinline__ float bce(float p, float t) {
    return -t * logf(p) - (1.0f - t) * logf(1.0f - p);
}

// init winner = -1 (NCELL ints) and clsmask = 0 (3*NCELL uints), 16B stores
__global__ void k_init(int4* winner4, uint4* clsmask4) {
    int idx = blockIdx.x * blockDim.x + threadIdx.x;
    if (idx < NCELL / 4) winner4[idx] = make_int4(-1, -1, -1, -1);
    if (idx < 3 * NCELL / 4) clsmask4[idx] = make_uint4(0u, 0u, 0u, 0u);
}

// per-target anchor matching + scatter into compact cell structures
__global__ void k_build(const float* __restrict__ xywh,
                        const int* __restrict__ cls,
                        const int* __restrict__ pi,
                        int* winner, unsigned* clsmask, float* tdata) {
    int idx = blockIdx.x * blockDim.x + threadIdx.x;
    if (idx >= BB * TT) return;
    int b = idx / TT;

    float x = xywh[idx * 4 + 0];
    float y = xywh[idx * 4 + 1];
    float w = xywh[idx * 4 + 2];
    float h = xywh[idx * 4 + 3];
    float bx = x * WW, by = y * HH, bw = w * WW, bh = h * HH;

    const float A[18] = {10,13,16,30,33,23,30,61,62,45,59,119,116,90,156,198,373,326};
    // scaled anchors: ANCHORS / (416/52) = ANCHORS * 0.125
    float best = -1.0f; int aid = 0;
    #pragma unroll
    for (int k = 0; k < 9; ++k) {
        float aw = A[2*k] * 0.125f, ah = A[2*k+1] * 0.125f;
        float inter = fminf(bw, aw) * fminf(bh, ah);
        float uni = bw * bh + aw * ah - inter;
        float iou = inter / uni;
        if (iou > best) { best = iou; aid = k; }
    }
    float aw = A[2*aid] * 0.125f, ah = A[2*aid+1] * 0.125f;
    int gx = (int)floorf(bx);
    int gy = (int)floorf(by);

    tdata[idx * 5 + 0] = bx - (float)gx;
    tdata[idx * 5 + 1] = by - (float)gy;
    tdata[idx * 5 + 2] = logf(bw / aw);
    tdata[idx * 5 + 3] = logf(bh / ah);
    tdata[idx * 5 + 4] = bw * bh / (float)(HH * WW);

    int i = *pi;
    bool valid = (aid / 3) == (2 - i);   // ANCHOR_MASK[i] = {3*(2-i), +1, +2}
    if (valid && gx >= 0 && gx < WW && gy >= 0 && gy < HH) {
        int pos = aid % 3;
        int cell = ((b * NB + pos) * HH + gy) * WW + gx;
        atomicMax(&winner[cell], idx);            // last target (largest t) wins
        int c = cls[idx];
        atomicOr(&clsmask[cell * 3 + (c >> 5)], 1u << (c & 31));
    }
}

// per-cell loss: conf for all cells; loc+cls only at positive cells.
// 4 cells/thread, all 7 accumulators reduced block-locally -> partials row.
__global__ void __launch_bounds__(NTHR_LOSS)
k_loss(const float* __restrict__ pred,
       const int* __restrict__ winner,
       const unsigned* __restrict__ clsmask,
       const float* __restrict__ tdata,
       float* __restrict__ partials) {
    int t = blockIdx.x * blockDim.x + threadIdx.x;
    int base = t * CELLS_PER_THR;
    float v[7] = {0.f, 0.f, 0.f, 0.f, 0.f, 0.f, 0.f};  // conf,lx,ly,lw,lh,cls,cnt

    if (base < NCELL) {
        int ba = base / SP;          // b*3 + a   (groups of 4 never cross: SP%4==0)
        int sp = base % SP;
        const float* pc = pred + (size_t)ba * CE * SP + sp;
        int4   wn4 = *(const int4*)(winner + base);
        float4 z4  = *(const float4*)(pc + 4 * SP);
        int   wns[4] = {wn4.x, wn4.y, wn4.z, wn4.w};
        float zs[4]  = {z4.x, z4.y, z4.z, z4.w};
        #pragma unroll
        for (int j = 0; j < 4; ++j) {
            float p4 = sigmoid_clamped(zs[j]);
            int wn = wns[j];
            if (wn >= 0) {
                v[0] += -logf(p4);       // bce(p4, 1)
                v[6] += 1.0f;
                const float* td = tdata + wn * 5;
                float scale = 2.0f - td[4];
                const float* pcj = pc + j;
                float z0 = pcj[0], z1 = pcj[SP], z2 = pcj[2 * SP], z3 = pcj[3 * SP];
                v[1] += bce(sigmoid_clamped(z0), td[0]) * scale;
                v[2] += bce(sigmoid_clamped(z1), td[1]) * scale;
                float dw = z2 - td[2];
                float dh = z3 - td[3];
                v[3] += dw * dw * scale;
                v[4] += dh * dh * scale;
                int cell = base + j;
                unsigned m0 = clsmask[cell * 3 + 0];
                unsigned m1 = clsmask[cell * 3 + 1];
                unsigned m2 = clsmask[cell * 3 + 2];
                float cls_s = 0.0f;
                #pragma unroll
                for (int c = 0; c < NC; ++c) {
                    float pp = sigmoid_clamped(pcj[(5 + c) * SP]);
                    unsigned bit = (c < 32) ? ((m0 >> c) & 1u)
                                 : (c < 64) ? ((m1 >> (c - 32)) & 1u)
                                            : ((m2 >> (c - 64)) & 1u);
                    cls_s += bce(pp, bit ? 1.0f : 0.0f);
                }
                v[5] += cls_s;
            } else {
                v[0] += -logf(1.0f - p4);  // bce(p4, 0)
            }
        }
    }

    // block reduction: wave64 shuffles, then LDS across the 4 waves
    #pragma unroll
    for (int off = 32; off > 0; off >>= 1) {
        #pragma unroll
        for (int k = 0; k < 7; ++k) v[k] += __shfl_down(v[k], off);
    }
    __shared__ float red[4][7];
    int wid = threadIdx.x >> 6, lane = threadIdx.x & 63;
    if (lane == 0) {
        #pragma unroll
        for (int k = 0; k < 7; ++k) red[wid][k] = v[k];
    }
    __syncthreads();
    if (threadIdx.x == 0) {
        #pragma unroll
        for (int k = 0; k < 7; ++k) {
            float s = red[0][k] + red[1][k] + red[2][k] + red[3][k];
            partials[blockIdx.x * 8 + k] = s;
        }
    }
}

// reduce NBLK_LOSS partial rows and finalize
__global__ void __launch_bounds__(256)
k_final(const float* __restrict__ partials,
        const int* __restrict__ pi,
        float* __restrict__ out) {
    float v[7] = {0.f, 0.f, 0.f, 0.f, 0.f, 0.f, 0.f};
    for (int r = threadIdx.x; r < NBLK_LOSS; r += blockDim.x) {
        #pragma unroll
        for (int k = 0; k < 7; ++k) v[k] += partials[r * 8 + k];
    }
    #pragma unroll
    for (int off = 32; off > 0; off >>= 1) {
        #pragma unroll
        for (int k = 0; k < 7; ++k) v[k] += __shfl_down(v[k], off);
    }
    __shared__ float red[4][7];
    int wid = threadIdx.x >> 6, lane = threadIdx.x & 63;
    if (lane == 0) {
        #pragma unroll
        for (int k = 0; k < 7; ++k) red[wid][k] = v[k];
    }
    __syncthreads();
    if (threadIdx.x == 0) {
        float conf_s = red[0][0] + red[1][0] + red[2][0] + red[3][0];
        float lx     = red[0][1] + red[1][1] + red[2][1] + red[3][1];
        float ly     = red[0][2] + red[1][2] + red[2][2] + red[3][2];
        float lw     = red[0][3] + red[1][3] + red[2][3] + red[3][3];
        float lh     = red[0][4] + red[1][4] + red[2][4] + red[3][4];
        float cls_s  = red[0][5] + red[1][5] + red[2][5] + red[3][5];
        float pos    = red[0][6] + red[1][6] + red[2][6] + red[3][6];

        float den = fmaxf(pos, 1.0f);
        float loc = (lx + ly + lw + lh) / den * 0.1f;
        float cls = cls_s / (den * (float)NC);
        int i = *pi;
        float bal = (i == 0) ? 0.4f : (i == 1) ? 1.0f : 4.0f;
        float conf = conf_s / (float)NCELL * bal;
        bool has = pos > 0.0f;
        float total = (has ? (loc * 0.05f + cls * 0.5f) : 0.0f) + conf;
        out[0] = total;
        out[1] = conf;
        out[2] = has ? loc : 0.0f;
        out[3] = has ? cls : 0.0f;
    }
}

extern "C" void kernel_launch(void* const* d_in, const int* in_sizes, int n_in,
                              void* d_out, int out_size, void* d_ws, size_t ws_size,
                              hipStream_t stream) {
    const int*   pi   = (const int*)d_in[0];
    const float* pred = (const float*)d_in[1];
    const float* xywh = (const float*)d_in[2];
    const int*   cls  = (const int*)d_in[3];
    float* out = (float*)d_out;

    char* ws = (char*)d_ws;
    int*      winner   = (int*)ws;                                  // NCELL ints
    unsigned* clsmask  = (unsigned*)(ws + (size_t)NCELL * 4);       // 3*NCELL uints
    float*    tdata    = (float*)(ws + (size_t)NCELL * 16);         // B*T*5 floats
    float*    partials = (float*)(ws + (size_t)NCELL * 16 + BB*TT*5*4); // NBLK_LOSS*8

    k_init <<<(3 * NCELL / 4 + 255) / 256, 256, 0, stream>>>((int4*)winner, (uint4*)clsmask);
    k_build<<<(BB * TT + 255) / 256, 256, 0, stream>>>(xywh, cls, pi, winner, clsmask, tdata);
    k_loss <<<NBLK_LOSS, NTHR_LOSS, 0, stream>>>(pred, winner, clsmask, tdata, partials);
    k_final<<<1, 256, 0, stream>>>(partials, pi, out);
}

// Round 3
// 20.531 us; speedup vs baseline: 3.0518x; 3.0518x over previous
//
#include <hip/hip_runtime.h>
#include <math.h>

#define BB 32
#define TT 50
#define HH 52
#define WW 52
#define NB 3
#define NC 80
#define CE 85            // 5 + NC
#define SP (HH*WW)       // 2704
#define NCELL (BB*NB*SP) // 259584
#define NT (BB*TT)       // 1600 targets
#define EPSF 1e-7f

#define NBLK 1014        // NCELL / 256
#define POSBLK 400       // NT / 4 waves-per-block

__device__ __forceinline__ float sigc(float z) {
    float p = 1.0f / (1.0f + expf(-z));
    return fminf(fmaxf(p, EPSF), 1.0f - EPSF);
}

__device__ __forceinline__ unsigned getbit(unsigned m0, unsigned m1, unsigned m2, int c) {
    return (c < 32) ? ((m0 >> c) & 1u)
         : (c < 64) ? ((m1 >> (c - 32)) & 1u)
                    : ((m2 >> (c - 64)) & 1u);
}

// anchor match for target w; returns packed (cell<<7)|class or -1
__device__ __forceinline__ int match_target(const float* __restrict__ xywh,
                                            const int* __restrict__ cls,
                                            int i, int w,
                                            float* obx, float* oby,
                                            float* obw, float* obh, int* oaid) {
    const float A[18] = {10,13,16,30,33,23,30,61,62,45,59,119,116,90,156,198,373,326};
    float bx = xywh[w*4+0] * WW, by = xywh[w*4+1] * HH;
    float bw = xywh[w*4+2] * WW, bh = xywh[w*4+3] * HH;
    int aid = 0; float best = -1.0f;
    #pragma unroll
    for (int k = 0; k < 9; ++k) {
        float aw = A[2*k] * 0.125f, ah = A[2*k+1] * 0.125f;  // ANCHORS/(416/52)
        float inter = fminf(bw, aw) * fminf(bh, ah);
        float iou = inter / (bw * bh + aw * ah - inter);
        if (iou > best) { best = iou; aid = k; }
    }
    *obx = bx; *oby = by; *obw = bw; *obh = bh; *oaid = aid;
    int gx = (int)floorf(bx), gy = (int)floorf(by);
    if ((aid / 3) == (2 - i) && gx >= 0 && gx < WW && gy >= 0 && gy < HH) {
        int b = w / TT;
        int cell = ((b * NB + (aid % 3)) * HH + gy) * WW + gx;
        return (cell << 7) | cls[w];
    }
    return -1;
}

// Fused kernel: dense negative-conf over all cells (every block) +
// wave-parallel positive-cell loss (blocks 0..POSBLK-1, one wave per target).
__global__ void __launch_bounds__(256)
k_main(const float* __restrict__ pred,
       const float* __restrict__ xywh,
       const int* __restrict__ cls,
       const int* __restrict__ pi,
       float* __restrict__ confpart,   // [NBLK]
       float* __restrict__ pospart) {  // [NT][8]
    __shared__ int epack[NT];
    __shared__ float sred[4];
    int tid = threadIdx.x;
    int t = blockIdx.x * 256 + tid;

    // --- dense conf, assume negative: bce(p4, 0) = -log(1-p4) ---
    int ba = t / SP, sp = t % SP;
    float z4 = pred[((size_t)ba * CE + 4) * SP + sp];
    float vconf = -logf(1.0f - sigc(z4));

    if (blockIdx.x < POSBLK) {
        int i = *pi;
        // phase 1: build match table in LDS (all blocks identical, deterministic)
        for (int w = tid; w < NT; w += 256) {
            float bx, by, bw, bh; int aid;
            epack[w] = match_target(xywh, cls, i, w, &bx, &by, &bw, &bh, &aid);
        }
        __syncthreads();

        // phase 2: one wave per target
        int lane = tid & 63;
        int wv = blockIdx.x * 4 + (tid >> 6);   // target index < NT
        int ep = epack[wv];
        float lx = 0, ly = 0, lw_ = 0, lh = 0, dconf = 0, clsum = 0;
        bool winner = false;
        if (ep >= 0) {
            int cell = ep >> 7;
            // scan all targets: OR class bits of same-cell matches, find max index
            unsigned m0 = 0, m1 = 0, m2 = 0;
            int mx = -1;
            #pragma unroll
            for (int k = 0; k < NT / 64; ++k) {
                int e = lane + 64 * k;
                int ee = epack[e];
                if (ee >= 0 && (ee >> 7) == cell) {
                    int c = ee & 127;
                    if (c < 32) m0 |= 1u << c;
                    else if (c < 64) m1 |= 1u << (c - 32);
                    else m2 |= 1u << (c - 64);
                    mx = max(mx, e);
                }
            }
            #pragma unroll
            for (int off = 32; off; off >>= 1) {
                m0 |= __shfl_xor(m0, off);
                m1 |= __shfl_xor(m1, off);
                m2 |= __shfl_xor(m2, off);
                mx = max(mx, __shfl_xor(mx, off));
            }
            winner = (mx == wv);   // wave-uniform
            if (winner) {
                // recompute target params (cheap, redundant across lanes)
                const float A[18] = {10,13,16,30,33,23,30,61,62,45,59,119,116,90,156,198,373,326};
                float bx, by, bw, bh; int aid;
                (void)match_target(xywh, cls, i, wv, &bx, &by, &bw, &bh, &aid);
                float aw = A[2*aid] * 0.125f, ah = A[2*aid+1] * 0.125f;
                float gx = floorf(bx), gy = floorf(by);
                float tx = bx - gx, ty = by - gy;
                float tw = logf(bw / aw), th = logf(bh / ah);
                float scale = 2.0f - bw * bh / (float)(HH * WW);
                int cba = cell / SP, csp = cell % SP;
                const float* pc = pred + (size_t)cba * CE * SP + csp;

                // channel `lane` (0..63) + channel 64+lane (lane<21): one load each
                float z = pc[lane * SP];
                float p = sigc(z);
                float prim;
                if (lane == 0)      prim = (-tx * logf(p) - (1.0f - tx) * logf(1.0f - p)) * scale;
                else if (lane == 1) prim = (-ty * logf(p) - (1.0f - ty) * logf(1.0f - p)) * scale;
                else if (lane == 2) { float d = z - tw; prim = d * d * scale; }
                else if (lane == 3) { float d = z - th; prim = d * d * scale; }
                else if (lane == 4) prim = -logf(p) + logf(1.0f - p);  // bce(p,1)-bce(p,0)
                else {
                    int c = lane - 5;  // class 0..58
                    prim = getbit(m0, m1, m2, c) ? -logf(p) : -logf(1.0f - p);
                }
                float sec = 0.0f;
                if (lane < CE - 64) {   // channels 64..84 -> classes 59..79
                    float z2 = pc[(64 + lane) * SP];
                    float p2 = sigc(z2);
                    sec = getbit(m0, m1, m2, 59 + lane) ? -logf(p2) : -logf(1.0f - p2);
                }
                float clsv = (lane >= 5 ? prim : 0.0f) + sec;
                #pragma unroll
                for (int off = 32; off; off >>= 1) clsv += __shfl_xor(clsv, off);
                lx    = __shfl(prim, 0);
                ly    = __shfl(prim, 1);
                lw_   = __shfl(prim, 2);
                lh    = __shfl(prim, 3);
                dconf = __shfl(prim, 4);
                clsum = clsv;
            }
        }
        if (lane == 0) {
            float4 a = make_float4(lx, ly, lw_, lh);
            float4 b = make_float4(dconf, clsum, winner ? 1.0f : 0.0f, 0.0f);
            *(float4*)(pospart + wv * 8)     = a;
            *(float4*)(pospart + wv * 8 + 4) = b;
        }
    }

    // --- block-reduce dense conf ---
    #pragma unroll
    for (int off = 32; off; off >>= 1) vconf += __shfl_down(vconf, off);
    if ((tid & 63) == 0) sred[tid >> 6] = vconf;
    __syncthreads();
    if (tid == 0) confpart[blockIdx.x] = sred[0] + sred[1] + sred[2] + sred[3];
}

__global__ void __launch_bounds__(256)
k_final(const float* __restrict__ confpart,
        const float* __restrict__ pospart,
        const int* __restrict__ pi,
        float* __restrict__ out) {
    int tid = threadIdx.x;
    float v[7] = {0.f, 0.f, 0.f, 0.f, 0.f, 0.f, 0.f};  // conf,lx,ly,lw,lh,cls,cnt
    for (int r = tid; r < NBLK; r += 256) v[0] += confpart[r];
    for (int r = tid; r < NT; r += 256) {
        float4 a = *(const float4*)(pospart + r * 8);
        float4 b = *(const float4*)(pospart + r * 8 + 4);
        v[1] += a.x; v[2] += a.y; v[3] += a.z; v[4] += a.w;
        v[0] += b.x; v[5] += b.y; v[6] += b.z;
    }
    #pragma unroll
    for (int off = 32; off; off >>= 1) {
        #pragma unroll
        for (int k = 0; k < 7; ++k) v[k] += __shfl_down(v[k], off);
    }
    __shared__ float red[4][7];
    int wid = tid >> 6, lane = tid & 63;
    if (lane == 0) {
        #pragma unroll
        for (int k = 0; k < 7; ++k) red[wid][k] = v[k];
    }
    __syncthreads();
    if (tid == 0) {
        float conf_s = red[0][0] + red[1][0] + red[2][0] + red[3][0];
        float lx     = red[0][1] + red[1][1] + red[2][1] + red[3][1];
        float ly     = red[0][2] + red[1][2] + red[2][2] + red[3][2];
        float lw     = red[0][3] + red[1][3] + red[2][3] + red[3][3];
        float lh     = red[0][4] + red[1][4] + red[2][4] + red[3][4];
        float cls_s  = red[0][5] + red[1][5] + red[2][5] + red[3][5];
        float pos    = red[0][6] + red[1][6] + red[2][6] + red[3][6];

        float den = fmaxf(pos, 1.0f);
        float loc = (lx + ly + lw + lh) / den * 0.1f;
        float clsL = cls_s / (den * (float)NC);
        int i = *pi;
        float bal = (i == 0) ? 0.4f : (i == 1) ? 1.0f : 4.0f;
        float conf = conf_s / (float)NCELL * bal;
        bool has = pos > 0.0f;
        float total = (has ? (loc * 0.05f + clsL * 0.5f) : 0.0f) + conf;
        out[0] = total;
        out[1] = conf;
        out[2] = has ? loc : 0.0f;
        out[3] = has ? clsL : 0.0f;
    }
}

extern "C" void kernel_launch(void* const* d_in, const int* in_sizes, int n_in,
                              void* d_out, int out_size, void* d_ws, size_t ws_size,
                              hipStream_t stream) {
    const int*   pi   = (const int*)d_in[0];
    const float* pred = (const float*)d_in[1];
    const float* xywh = (const float*)d_in[2];
    const int*   cls  = (const int*)d_in[3];
    float* out = (float*)d_out;

    char* ws = (char*)d_ws;
    float* confpart = (float*)ws;                 // NBLK floats
    float* pospart  = (float*)(ws + 4096);        // NT*8 floats (16B aligned)

    k_main <<<NBLK, 256, 0, stream>>>(pred, xywh, cls, pi, confpart, pospart);
    k_final<<<1, 256, 0, stream>>>(confpart, pospart, pi, out);
}